// Round 3
// baseline (599.044 us; speedup 1.0000x reference)
//
#include <hip/hip_runtime.h>
#include <hip/hip_bf16.h>

#define B_  2
#define S_  2048
#define D_  2048
#define H_  16
#define DH_ 128
#define M_  (B_*S_)   // 4096

typedef __hip_bfloat16 bf16;
typedef float v4f __attribute__((ext_vector_type(4)));
typedef short v8s __attribute__((ext_vector_type(8)));

__device__ __forceinline__ short f2s(float x) {
  bf16 h = __float2bfloat16(x);
  return *reinterpret_cast<const short*>(&h);
}
// load 8 contiguous f32 elems, convert to bf16 bits
__device__ __forceinline__ v8s ld8(const float* p) {
  v4f a = *reinterpret_cast<const v4f*>(p);
  v4f b = *reinterpret_cast<const v4f*>(p + 4);
  v8s r = { f2s(a[0]), f2s(a[1]), f2s(a[2]), f2s(a[3]),
            f2s(b[0]), f2s(b[1]), f2s(b[2]), f2s(b[3]) };
  return r;
}
__device__ __forceinline__ void store_out(bf16* p, float v)  { *p = __float2bfloat16(v); }
__device__ __forceinline__ void store_out(float* p, float v) { *p = v; }

// async 16B global->LDS (direct, no VGPR round-trip). LDS dest is
// wave-uniform base + lane*16; global src is per-lane.
__device__ __forceinline__ void gll16(const bf16* g, bf16* l) {
  __builtin_amdgcn_global_load_lds((const __attribute__((address_space(1))) void*)g,
                                   (__attribute__((address_space(3))) void*)l,
                                   16, 0, 0);
}

// streaming f32 -> bf16 convert, 8 elems/thread
__global__ __launch_bounds__(256) void cvt_f32_bf16(const float* __restrict__ in,
                                                    bf16* __restrict__ out, int n8) {
  int i = blockIdx.x * 256 + threadIdx.x;
  if (i >= n8) return;
  *reinterpret_cast<v8s*>(out + (size_t)i * 8) = ld8(in + (size_t)i * 8);
}

// ---------------------------------------------------------------------------
// 2-phase double-buffered GEMM (T3 minimum recipe, m230/m248-verified schedule)
// C = A @ W^T + bias ; A [M,2048] bf16 row-major, W [N,2048] bf16 row-major.
// BM=256, BN=128, BK=64, 512 threads (8 waves: wm=wave>>1 in 0..3, wn=wave&1).
// Per-wave output 64x64 = 4x4 fragments of 16x16. LDS 96 KiB (1 block/CU).
// MODE 0: QK fused (N=4096; n<2048 -> Q scaled, else K) -> [B,H,S,dh]
// MODE 2: V -> [B,H,dh,S]
// MODE 3: plain [M,N] f32 out
// ---------------------------------------------------------------------------
template <int MODE, typename TOUT>
__global__ __launch_bounds__(512, 2) void gemm2(const bf16* __restrict__ A,
                                                const bf16* __restrict__ W,
                                                const float* __restrict__ bias0,
                                                const float* __restrict__ bias1,
                                                TOUT* __restrict__ out0,
                                                TOUT* __restrict__ out1) {
  __shared__ __align__(16) bf16 As[2][256 * 64];   // 64 KiB
  __shared__ __align__(16) bf16 Bs[2][128 * 64];   // 32 KiB
  const int tid  = threadIdx.x;
  const int lane = tid & 63, wave = tid >> 6;
  const int wm = wave >> 1, wn = wave & 1;
  const int quad = lane >> 4, l16 = lane & 15;
  const int bm = blockIdx.y * 256, bn = blockIdx.x * 128;

  const bf16* Arow = A + (size_t)bm * D_;
  const bf16* Wrow = W + (size_t)bn * D_;

  v4f acc[4][4] = {};

  // prologue: stage tile 0 into buf 0
  {
#pragma unroll
    for (int j = 0; j < 4; ++j) {
      const int blk = j * 512 + tid;
      gll16(Arow + (size_t)(blk >> 3) * D_ + ((blk & 7) << 3),
            &As[0][(j * 512 + wave * 64) * 8]);
    }
#pragma unroll
    for (int j = 0; j < 2; ++j) {
      const int blk = j * 512 + tid;
      gll16(Wrow + (size_t)(blk >> 3) * D_ + ((blk & 7) << 3),
            &Bs[0][(j * 512 + wave * 64) * 8]);
    }
  }
  asm volatile("s_waitcnt vmcnt(0)" ::: "memory");
  __syncthreads();

  constexpr int NT = D_ / 64;   // 32 K-tiles
  int cur = 0;
  for (int t = 0; t < NT; ++t) {
    // issue next-tile staging into the other buffer (latency hides under MFMA)
    if (t + 1 < NT) {
      const int k0 = (t + 1) * 64;
      const int nb = cur ^ 1;
#pragma unroll
      for (int j = 0; j < 4; ++j) {
        const int blk = j * 512 + tid;
        gll16(Arow + (size_t)(blk >> 3) * D_ + k0 + ((blk & 7) << 3),
              &As[nb][(j * 512 + wave * 64) * 8]);
      }
#pragma unroll
      for (int j = 0; j < 2; ++j) {
        const int blk = j * 512 + tid;
        gll16(Wrow + (size_t)(blk >> 3) * D_ + k0 + ((blk & 7) << 3),
              &Bs[nb][(j * 512 + wave * 64) * 8]);
      }
    }
    // compute current tile
    v8s af[4][2], bfr[4][2];
#pragma unroll
    for (int mi = 0; mi < 4; ++mi)
#pragma unroll
      for (int kk = 0; kk < 2; ++kk)
        af[mi][kk] = *reinterpret_cast<const v8s*>(
            &As[cur][(wm * 64 + mi * 16 + l16) * 64 + kk * 32 + quad * 8]);
#pragma unroll
    for (int ni = 0; ni < 4; ++ni)
#pragma unroll
      for (int kk = 0; kk < 2; ++kk)
        bfr[ni][kk] = *reinterpret_cast<const v8s*>(
            &Bs[cur][(wn * 64 + ni * 16 + l16) * 64 + kk * 32 + quad * 8]);
#pragma unroll
    for (int kk = 0; kk < 2; ++kk)
#pragma unroll
      for (int mi = 0; mi < 4; ++mi)
#pragma unroll
        for (int ni = 0; ni < 4; ++ni)
          acc[mi][ni] = __builtin_amdgcn_mfma_f32_16x16x32_bf16(
              af[mi][kk], bfr[ni][kk], acc[mi][ni], 0, 0, 0);
    // one drain+barrier per K-step: staged tile resident AND buf[cur] free
    asm volatile("s_waitcnt vmcnt(0)" ::: "memory");
    __syncthreads();
    cur ^= 1;
  }

  constexpr float QSCALE = 0.12752003912f;  // 1/sqrt(128) * log2(e)
  const int proj = (MODE == 0) ? (bn >> 11) : 0;       // block-uniform
  const float* bias = (proj ? bias1 : bias0);
  TOUT* outp = (proj ? out1 : out0);
  const int bnl = bn & 2047;
#pragma unroll
  for (int ni = 0; ni < 4; ++ni) {
    const int nl = bnl + wn * 64 + ni * 16 + l16;      // 0..2047 within proj
    const float bv = bias[nl];
#pragma unroll
    for (int mi = 0; mi < 4; ++mi) {
      const int m0 = bm + wm * 64 + mi * 16 + quad * 4;
#pragma unroll
      for (int r = 0; r < 4; ++r) {
        const int m = m0 + r;           // row m: (b,s). col nl: (h,d)
        float v = acc[mi][ni][r] + bv;
        size_t idx;
        if (MODE == 0) {
          if (!proj) v *= QSCALE;
          int b = m >> 11, s = m & (S_ - 1);
          int h = nl >> 7, d = nl & (DH_ - 1);
          idx = ((size_t)(b * H_ + h) * S_ + s) * DH_ + d;
        } else if (MODE == 2) {
          int b = m >> 11, s = m & (S_ - 1);
          int h = nl >> 7, d = nl & (DH_ - 1);
          idx = ((size_t)(b * H_ + h) * DH_ + d) * S_ + s;
        } else {
          idx = (size_t)m * D_ + nl;
        }
        store_out(outp + idx, v);
      }
    }
  }
}

// Flash attention, causal. Q/K: [B,H,S,dh], Vt: [B,H,dh,S] (all bf16). Out: [B,S,D] bf16.
// Block = 128 Q rows (8 waves x 16 rows), K-tile = 64 keys, 512 threads.
// 2-phase: double-buffered K/V staged via global_load_lds with XOR-swizzled
// GLOBAL source; reads apply the same XOR (rule 21). One barrier per K-tile:
// stage(t+1) issued before compute(t), vmcnt(0)+barrier at iter end.
#define QBLK 128
__global__ __launch_bounds__(512, 2) void attn_fused(const bf16* __restrict__ Q,
                                                     const bf16* __restrict__ K,
                                                     const bf16* __restrict__ Vt,
                                                     bf16* __restrict__ Oa) {
  __shared__ __align__(16) bf16 Ks[2][64 * 128];  // [key][d] linear; blk c holds global c^(key&7)
  __shared__ __align__(16) bf16 Vs[2][128 * 64];  // [d][key] linear; blk c holds global c^(d&7)
  __shared__ __align__(16) bf16 Ps[8][16 * 72];   // per-wave P, padded stride 72
  const int tid  = threadIdx.x;
  const int lane = tid & 63, wave = tid >> 6;
  const int quad = lane >> 4, l16 = lane & 15;
  const int swz  = l16 & 7;
  // longest-first: work per block ~ qt, launch big blocks first.
  const int qt = (int)gridDim.x - 1 - (int)blockIdx.x;
  const int bh = blockIdx.y;
  const int b = bh >> 4, h = bh & 15;
  const bf16* Qh = Q  + (size_t)bh * S_ * DH_;
  const bf16* Kh = K  + (size_t)bh * S_ * DH_;
  const bf16* Vh = Vt + (size_t)bh * DH_ * S_;

  const int qrow0 = qt * QBLK + wave * 16;
  v8s qf[4];
#pragma unroll
  for (int kk = 0; kk < 4; ++kk)
    qf[kk] = *reinterpret_cast<const v8s*>(&Qh[(size_t)(qrow0 + l16) * DH_ + kk * 32 + quad * 8]);

  v4f acc_o[8] = {};
  float m_i[4], l_i[4];
#pragma unroll
  for (int r = 0; r < 4; ++r) { m_i[r] = -1.0e30f; l_i[r] = 0.f; }

  const int nkt = 2 * qt + 2;

  // prologue: stage tile 0 into buf 0
#pragma unroll
  for (int rr = 0; rr < 2; ++rr) {
    const int g = rr * 512 + tid;
    const int krow = g >> 4, kc = g & 15;           // K: 16 x 16B blocks/row
    gll16(Kh + (size_t)krow * DH_ + (((kc ^ (krow & 7)) << 3)),
          &Ks[0][(rr * 512 + wave * 64) * 8]);
    const int vrow = g >> 3, vc = g & 7;            // V: 8 x 16B blocks/row
    gll16(Vh + (size_t)vrow * S_ + ((vc ^ (vrow & 7)) << 3),
          &Vs[0][(rr * 512 + wave * 64) * 8]);
  }
  asm volatile("s_waitcnt vmcnt(0)" ::: "memory");
  __syncthreads();

  int cur = 0;
  for (int kt = 0; kt < nkt; ++kt) {
    const int kbase = kt * 64;
    // issue next-tile staging into the other buffer
    if (kt + 1 < nkt) {
      const int nbase = kbase + 64;
      const int nb = cur ^ 1;
#pragma unroll
      for (int rr = 0; rr < 2; ++rr) {
        const int g = rr * 512 + tid;
        const int krow = g >> 4, kc = g & 15;
        gll16(Kh + (size_t)(nbase + krow) * DH_ + (((kc ^ (krow & 7)) << 3)),
              &Ks[nb][(rr * 512 + wave * 64) * 8]);
        const int vrow = g >> 3, vc = g & 7;
        gll16(Vh + (size_t)vrow * S_ + nbase + (((vc ^ (vrow & 7)) << 3)),
              &Vs[nb][(rr * 512 + wave * 64) * 8]);
      }
    }

    const bool active = (kbase <= qrow0 + 15);
    if (active) {
      // S = Q K^T (Q pre-scaled by 1/sqrt(dh)*log2e)
      v4f sc[4];
      __builtin_amdgcn_s_setprio(1);
#pragma unroll
      for (int nt = 0; nt < 4; ++nt) {
        v4f a = {};
#pragma unroll
        for (int kk = 0; kk < 4; ++kk) {
          v8s kf = *reinterpret_cast<const v8s*>(
              &Ks[cur][(nt * 16 + l16) * 128 + (((kk * 4 + quad) ^ swz) << 3)]);
          a = __builtin_amdgcn_mfma_f32_16x16x32_bf16(qf[kk], kf, a, 0, 0, 0);
        }
        sc[nt] = a;
      }
      __builtin_amdgcn_s_setprio(0);
      if (kbase + 63 > qrow0) {   // diagonal tile: causal mask
#pragma unroll
        for (int nt = 0; nt < 4; ++nt)
#pragma unroll
          for (int r = 0; r < 4; ++r) {
            int kc2 = kbase + nt * 16 + l16;
            int qr = qrow0 + quad * 4 + r;
            if (kc2 > qr) sc[nt][r] = -1.0e30f;
          }
      }
      // online softmax; C-layout: row = quad*4 + r, col = nt*16 + l16
#pragma unroll
      for (int r = 0; r < 4; ++r) {
        float mx = fmaxf(fmaxf(sc[0][r], sc[1][r]), fmaxf(sc[2][r], sc[3][r]));
        mx = fmaxf(mx, __shfl_xor(mx, 1));
        mx = fmaxf(mx, __shfl_xor(mx, 2));
        mx = fmaxf(mx, __shfl_xor(mx, 4));
        mx = fmaxf(mx, __shfl_xor(mx, 8));
        // T13 defer-max: only rescale when max grew by >8 (log2 domain)
        if (mx > m_i[r] + 8.0f) {
          float alpha = exp2f(m_i[r] - mx);
          m_i[r] = mx;
          l_i[r] *= alpha;
#pragma unroll
          for (int nt8 = 0; nt8 < 8; ++nt8) acc_o[nt8][r] *= alpha;
        }
        const float mm = m_i[r];
        float s0 = exp2f(sc[0][r] - mm);
        float s1 = exp2f(sc[1][r] - mm);
        float s2 = exp2f(sc[2][r] - mm);
        float s3 = exp2f(sc[3][r] - mm);
        sc[0][r] = s0; sc[1][r] = s1; sc[2][r] = s2; sc[3][r] = s3;
        float t = s0 + s1 + s2 + s3;
        t += __shfl_xor(t, 1); t += __shfl_xor(t, 2);
        t += __shfl_xor(t, 4); t += __shfl_xor(t, 8);
        l_i[r] += t;
      }
      // P: C-layout regs -> per-wave LDS (bf16) -> A-layout frags
#pragma unroll
      for (int nt = 0; nt < 4; ++nt)
#pragma unroll
        for (int r = 0; r < 4; ++r)
          Ps[wave][(quad * 4 + r) * 72 + nt * 16 + l16] = __float2bfloat16(sc[nt][r]);
      // own-wave write->read ordering only; no cross-wave dep -> no barrier
      asm volatile("s_waitcnt lgkmcnt(0)" ::: "memory");
      // O += P V
      __builtin_amdgcn_s_setprio(1);
#pragma unroll
      for (int kk2 = 0; kk2 < 2; ++kk2) {
        v8s pf = *reinterpret_cast<const v8s*>(&Ps[wave][l16 * 72 + kk2 * 32 + quad * 8]);
#pragma unroll
        for (int nt8 = 0; nt8 < 8; ++nt8) {
          v8s vf = *reinterpret_cast<const v8s*>(
              &Vs[cur][(nt8 * 16 + l16) * 64 + (((kk2 * 4 + quad) ^ swz) << 3)]);
          acc_o[nt8] = __builtin_amdgcn_mfma_f32_16x16x32_bf16(pf, vf, acc_o[nt8], 0, 0, 0);
        }
      }
      __builtin_amdgcn_s_setprio(0);
    }
    // single drain+barrier per tile: next tile resident AND buf[cur] free
    asm volatile("s_waitcnt vmcnt(0)" ::: "memory");
    __syncthreads();
    cur ^= 1;
  }

#pragma unroll
  for (int r = 0; r < 4; ++r) {
    const float inv = 1.0f / l_i[r];
    const int srow = qrow0 + quad * 4 + r;
#pragma unroll
    for (int nt8 = 0; nt8 < 8; ++nt8)
      Oa[((size_t)b * S_ + srow) * D_ + h * DH_ + nt8 * 16 + l16] =
          __float2bfloat16(acc_o[nt8][r] * inv);
  }
}

extern "C" void kernel_launch(void* const* d_in, const int* in_sizes, int n_in,
                              void* d_out, int out_size, void* d_ws, size_t ws_size,
                              hipStream_t stream) {
  // Canary: all-zero output (absmax exactly 3.5625) signals a tripped assumption.
  if (n_in != 9 ||
      in_sizes[0] != M_ * D_ ||
      in_sizes[1] != D_ * D_ || in_sizes[2] != D_ ||
      in_sizes[3] != D_ * D_ || in_sizes[4] != D_ ||
      in_sizes[5] != D_ * D_ || in_sizes[6] != D_ ||
      in_sizes[7] != D_ * D_ || in_sizes[8] != D_ ||
      out_size != M_ * D_)
    return;

  const float* x  = (const float*)d_in[0];
  const float* Wq = (const float*)d_in[1];
  const float* bq = (const float*)d_in[2];
  const float* Wk = (const float*)d_in[3];
  const float* bk = (const float*)d_in[4];
  const float* Wv = (const float*)d_in[5];
  const float* bv = (const float*)d_in[6];
  const float* Wo = (const float*)d_in[7];
  const float* bo = (const float*)d_in[8];
  float* out = (float*)d_out;   // OUTPUT IS FLOAT32 (reference output dtype)

  const size_t NT = (size_t)M_ * D_;   // 8388608 elems per tensor
  const size_t WN = (size_t)D_ * D_;   // 4194304 elems per weight
  // Buffer plan:
  //   d_out (33.6 MB f32):  [0,16.8) qws (bf16 Q), [16.8,33.6) x_bf16
  //     both dead before the final GEMM overwrites d_out.
  //   ws (48 MiB): kws | vtw | aws
  //     WqWk-cat (16.8 MB) lives in aws before QK GEMM; Wv reuses aws[0:8.4)
  //     before V GEMM; aws becomes the attn output after (W's dead);
  //     Wo parks in kws (K dead after attn).
  bf16* qws   = (bf16*)d_out;
  bf16* xbf   = (bf16*)d_out + NT;
  bf16* kws   = (bf16*)d_ws;
  bf16* vtw   = kws + NT;
  bf16* aws   = vtw + NT;
  bf16* wqk   = aws;            // [4096][2048] bf16 concat
  bf16* wv_s  = aws;            // [2048][2048]
  bf16* wo_s  = kws;            // [2048][2048] (post-attn)

  const int N8X = M_ * D_ / 8;   // 1048576
  const int N8W = D_ * D_ / 8;   // 524288

  dim3 bb(256);
  cvt_f32_bf16<<<N8X / 256, bb, 0, stream>>>(x, xbf, N8X);
  cvt_f32_bf16<<<N8W / 256, bb, 0, stream>>>(Wq, wqk, N8W);
  cvt_f32_bf16<<<N8W / 256, bb, 0, stream>>>(Wk, wqk + WN, N8W);

  // QK fused: N=4096, grid 32x16 = 512 blocks (2 exact rounds at 1 blk/CU)
  gemm2<0, bf16><<<dim3(32, 16), dim3(512), 0, stream>>>(xbf, wqk, bq, bk, qws, kws);

  cvt_f32_bf16<<<N8W / 256, bb, 0, stream>>>(Wv, wv_s, N8W);
  gemm2<2, bf16><<<dim3(16, 16), dim3(512), 0, stream>>>(xbf, wv_s, bv, bv, vtw, vtw);

  attn_fused<<<dim3(S_ / QBLK, B_ * H_), dim3(512), 0, stream>>>(qws, kws, vtw, aws);

  cvt_f32_bf16<<<N8W / 256, bb, 0, stream>>>(Wo, wo_s, N8W);
  gemm2<3, float><<<dim3(16, 16), dim3(512), 0, stream>>>(aws, wo_s, bo, bo, out, out);
}